// Round 4
// baseline (783.739 us; speedup 1.0000x reference)
//
#include <hip/hip_runtime.h>

// LossClassInOut: pred, pseudo are [N=2e6, C=32] fp32. Output: scalar fp32.
//
// ws float layout (2176 floats):
//   [0,32) counts_a | [32,64) counts_b | [64,1088) sums_a[32][32]
//   [1088,2112) sums_b[32][32] | [2112,2144) intra_a | [2144,2176) intra_b
//
// R6 (= R5 re-bench after infra failure): R4 showed the global_load_lds DMA
// path is a shared per-CU throughput cap (~5 B/cyc/CU; occupancy doubling
// moved perf only 11%, and an L3-fed replay ran the same time). This version
// stages via registers (global_load_dwordx4, the 10 B/cyc/CU path) +
// ds_write_b128 (T14 issue-early/write-late). Register staging orders writes
// after the current tile's reads within the wave, so tiles are SINGLE-
// buffered: LDS 74->42KB -> 3 blocks/CU (NBLK=768, 3 waves/SIMD).
// __launch_bounds__(256,3) keeps the allocator from spilling the 32
// in-flight VGPRs (the R0 trap). Explicit vmcnt(0)+sched_barrier before the
// write-late ds_writes makes the load->write ordering explicit.

constexpr int CDIM = 32;
constexpr int NBLK = 768;            // 3 blocks/CU (42KB LDS each), all resident
constexpr int ROWS_PER_BLOCK = 128;  // 4 waves * 32 rows

typedef __attribute__((ext_vector_type(8)))  short bf16x8;
typedef __attribute__((ext_vector_type(16))) float f32x16;

__device__ __forceinline__ unsigned short f2bf(float f) {
    unsigned u = __float_as_uint(f);
    return (unsigned short)((u + 0x7FFFu + ((u >> 16) & 1u)) >> 16);  // RNE
}
// float-index into a 32x32 tile stored as 128B rows with 16B-block XOR swizzle
__device__ __forceinline__ int toff(int r, int kb) {
    return r * 32 + ((kb ^ (r & 7)) * 4);
}
// np.argmax over 16 values (4 float4), strict > keeps first index
__device__ __forceinline__ void argmax16(const float4* v, float& bv, int& bi) {
    float b = v[0].x; int i = 0;
#pragma unroll
    for (int k = 0; k < 4; k++) {
        int k4 = k * 4;
        if (v[k].x > b) { b = v[k].x; i = k4; }
        if (v[k].y > b) { b = v[k].y; i = k4 + 1; }
        if (v[k].z > b) { b = v[k].z; i = k4 + 2; }
        if (v[k].w > b) { b = v[k].w; i = k4 + 3; }
    }
    bv = b; bi = i;
}
// combine half-row argmax across lane pair (lw ^ 32); ties favor lower col
__device__ __forceinline__ int combine_argmax(float bv, int bc, int h2) {
    float ov = __shfl_xor(bv, 32);
    int   oc = __shfl_xor(bc, 32);
    float vlo = h2 ? ov : bv, vhi = h2 ? bv : ov;
    int   clo = h2 ? oc : bc, chi = h2 ? bc : oc;
    return (vhi > vlo) ? chi : clo;
}

// Issue the 4 global loads of one 32x32 tile into registers. The lane's
// source block is pre-XOR'd so a LINEAR ds_write (lane*16B) lands content
// where toff()'s swizzled reads expect it (rule 21 both-sides pattern).
__device__ __forceinline__ void load_tile_regs(const float4* __restrict__ g4,
                                               float4* R, long long wb,
                                               int nrows, int lw)
{
    const int rl = lw >> 3;
    const int kb = (lw & 7) ^ (rl & 7);    // pre-swizzled source block
#pragma unroll
    for (int i = 0; i < 4; i++) {
        long long r = wb + 8 * i + rl; if (r >= nrows) r = nrows - 1;
        R[i] = g4[r * 8 + kb];
    }
}
__device__ __forceinline__ void write_tile(float* lds, const float4* R, int lw) {
#pragma unroll
    for (int i = 0; i < 4; i++)
        *(float4*)&lds[i * 256 + lw * 4] = R[i];
}

__global__ __launch_bounds__(256, 3) void pass1_kernel(
    const float* __restrict__ pred, const float* __restrict__ pseudo,
    float* __restrict__ ws, int nrows)
{
    __shared__ __align__(16) float ptile[4][32 * 32];
    __shared__ __align__(16) float qtile[4][32 * 32];
    __shared__ __align__(16) unsigned short labs[4][32];
    __shared__ float sa[CDIM][33], sb[CDIM][33];
    __shared__ float ca[CDIM], cb[CDIM];

    const int t = threadIdx.x, wv = t >> 6, lw = t & 63;
    for (int i = t; i < CDIM * 33; i += 256) { (&sa[0][0])[i] = 0.f; (&sb[0][0])[i] = 0.f; }
    if (t < CDIM) { ca[t] = 0.f; cb[t] = 0.f; }
    __syncthreads();

    const int n = lw & 31, h2 = lw >> 5;   // mfma/argmax lane coords

    f32x16 accP, accQ;
#pragma unroll
    for (int g = 0; g < 16; g++) { accP[g] = 0.f; accQ[g] = 0.f; }

    const float4* p4 = (const float4*)pred;
    const float4* q4 = (const float4*)pseudo;
    const long long rps = (long long)NBLK * ROWS_PER_BLOCK;
    const int nsweep = (int)((nrows + rps - 1) / rps);
    const long long wbase0 = (long long)blockIdx.x * ROWS_PER_BLOCK + wv * 32;

    float* pt = ptile[wv];
    float* qt = qtile[wv];

    // prologue: stage sweep 0
    float4 P[4], Q[4];
    load_tile_regs(p4, P, wbase0, nrows, lw);
    load_tile_regs(q4, Q, wbase0, nrows, lw);
    asm volatile("s_waitcnt vmcnt(0)" ::: "memory");
    write_tile(pt, P, lw);
    write_tile(qt, Q, lw);

    for (int s = 0; s < nsweep; s++) {
        const long long wb = wbase0 + (long long)s * rps;
        const bool pf = (s + 1 < nsweep);
        if (pf) {                          // issue next sweep's loads EARLY
            load_tile_regs(p4, P, wb + rps, nrows, lw);
            load_tile_regs(q4, Q, wb + rps, nrows, lw);
        }

        // pair-split labels: lane lw scans cols 16*h2..16*h2+15 of row lw&31
        const int r = n;                   // tile row this lane helps with
        const bool valid = (wb + r) < nrows;
        int la, lbv;
        {
            float4 v_[4];
#pragma unroll
            for (int k = 0; k < 4; k++) v_[k] = *(const float4*)&qt[toff(r, 4 * h2 + k)];
            float bv; int bi; argmax16(v_, bv, bi);
            la = combine_argmax(bv, 16 * h2 + bi, h2);
#pragma unroll
            for (int k = 0; k < 4; k++) v_[k] = *(const float4*)&pt[toff(r, 4 * h2 + k)];
            argmax16(v_, bv, bi);
            lbv = combine_argmax(bv, 16 * h2 + bi, h2);
        }
        if (h2 == 0) {
            labs[wv][r] = (unsigned short)((valid ? la : 0xFF) | ((valid ? lbv : 0xFF) << 8));
            unsafeAtomicAdd(&ca[la & 31], valid ? 1.f : 0.f);
            unsafeAtomicAdd(&cb[lbv & 31], valid ? 1.f : 0.f);
        }

        // one-hot MFMA: sums[c][d] += onehot(label)^T * X over 32 rows (K-tiles of 16)
#pragma unroll
        for (int kt = 0; kt < 2; kt++) {
            const uint4 lv = *(const uint4*)&labs[wv][kt * 16 + h2 * 8];  // 8 rows' packed labels
            bf16x8 aP, aQ, bP, bQ;
#pragma unroll
            for (int j = 0; j < 8; j++) {
                unsigned w32 = ((const unsigned*)&lv)[j >> 1];
                unsigned pr  = (w32 >> ((j & 1) * 16)) & 0xFFFFu;
                int laj = (int)(pr & 0xFF), lbj = (int)(pr >> 8);
                aP[j] = (short)((laj == n) ? 0x3F80 : 0);   // bf16 1.0 / 0.0
                aQ[j] = (short)((lbj == n) ? 0x3F80 : 0);
                int rr = kt * 16 + h2 * 8 + j;
                int o = rr * 32 + (((n >> 2) ^ (rr & 7)) * 4) + (n & 3);
                bP[j] = (short)f2bf(pt[o]);
                bQ[j] = (short)f2bf(qt[o]);
            }
            accP = __builtin_amdgcn_mfma_f32_32x32x16_bf16(aP, bP, accP, 0, 0, 0);
            accQ = __builtin_amdgcn_mfma_f32_32x32x16_bf16(aQ, bQ, accQ, 0, 0, 0);
        }

        if (pf) {                          // write-late: next tile into the
            asm volatile("s_waitcnt vmcnt(0)" ::: "memory");
            __builtin_amdgcn_sched_barrier(0);
            write_tile(pt, P, lw);         // (single) buffer after all reads
            write_tile(qt, Q, lw);
        }
    }

    // fold wave accumulators: C/D layout col=lane&31, row=(reg&3)+8*(reg>>2)+4*(lane>>5)
#pragma unroll
    for (int g = 0; g < 16; g++) {
        int c = (g & 3) + 8 * (g >> 2) + 4 * h2;
        unsafeAtomicAdd(&sa[c][n], accP[g]);
        unsafeAtomicAdd(&sb[c][n], accQ[g]);
    }
    __syncthreads();
    for (int i = t; i < CDIM * CDIM; i += 256) {
        int c = i >> 5, d = i & 31;
        unsafeAtomicAdd(&ws[64 + i],        sa[c][d]);
        unsafeAtomicAdd(&ws[64 + 1024 + i], sb[c][d]);
    }
    if (t < CDIM) { unsafeAtomicAdd(&ws[t], ca[t]); unsafeAtomicAdd(&ws[32 + t], cb[t]); }
}

__global__ __launch_bounds__(256, 3) void pass2_kernel(
    const float* __restrict__ pred, const float* __restrict__ pseudo,
    float* __restrict__ ws, int nrows)
{
    __shared__ __align__(16) float ptile[4][32 * 32];
    __shared__ __align__(16) float qtile[4][32 * 32];
    __shared__ __align__(16) float mA[1024], mB[1024];
    __shared__ float ia[CDIM], ib[CDIM];

    const int t = threadIdx.x, wv = t >> 6, lw = t & 63;
    for (int i = t; i < 1024; i += 256) {     // means, stored XOR-swizzled like tiles
        int c = i >> 5, d = i & 31;
        int o = c * 32 + (((d >> 2) ^ (c & 7)) * 4) + (d & 3);
        mA[o] = ws[64 + i]        / fmaxf(ws[c],      1.f);
        mB[o] = ws[64 + 1024 + i] / fmaxf(ws[32 + c], 1.f);
    }
    if (t < CDIM) { ia[t] = 0.f; ib[t] = 0.f; }
    __syncthreads();

    const int n = lw & 31, h2 = lw >> 5;

    const float4* p4 = (const float4*)pred;
    const float4* q4 = (const float4*)pseudo;
    const long long rps = (long long)NBLK * ROWS_PER_BLOCK;
    const int nsweep = (int)((nrows + rps - 1) / rps);
    const long long wbase0 = (long long)blockIdx.x * ROWS_PER_BLOCK + wv * 32;

    float* pt = ptile[wv];
    float* qt = qtile[wv];

    float4 P[4], Q[4];
    load_tile_regs(p4, P, wbase0, nrows, lw);
    load_tile_regs(q4, Q, wbase0, nrows, lw);
    asm volatile("s_waitcnt vmcnt(0)" ::: "memory");
    write_tile(pt, P, lw);
    write_tile(qt, Q, lw);

    for (int s = 0; s < nsweep; s++) {
        const long long wb = wbase0 + (long long)s * rps;
        const bool pf = (s + 1 < nsweep);
        if (pf) {
            load_tile_regs(p4, P, wb + rps, nrows, lw);
            load_tile_regs(q4, Q, wb + rps, nrows, lw);
        }

        const int r = n;
        const bool valid = (wb + r) < nrows;
        float4 pr_[4], qr_[4];
#pragma unroll
        for (int k = 0; k < 4; k++) { pr_[k] = *(const float4*)&pt[toff(r, 4 * h2 + k)];
                                      qr_[k] = *(const float4*)&qt[toff(r, 4 * h2 + k)]; }
        float bv; int bi;
        argmax16(qr_, bv, bi);
        const int la = combine_argmax(bv, 16 * h2 + bi, h2) & 31;  // pseudo label -> segments pred
        argmax16(pr_, bv, bi);
        const int lb = combine_argmax(bv, 16 * h2 + bi, h2) & 31;  // pred label   -> segments pseudo

        float sA = 0.f, sB = 0.f;
#pragma unroll
        for (int k = 0; k < 4; k++) {
            float4 m4 = *(const float4*)&mA[la * 32 + (((4 * h2 + k) ^ (la & 7)) * 4)];
            sA += fabsf(pr_[k].x - m4.x) + fabsf(pr_[k].y - m4.y)
                + fabsf(pr_[k].z - m4.z) + fabsf(pr_[k].w - m4.w);
            float4 n4 = *(const float4*)&mB[lb * 32 + (((4 * h2 + k) ^ (lb & 7)) * 4)];
            sB += fabsf(qr_[k].x - n4.x) + fabsf(qr_[k].y - n4.y)
                + fabsf(qr_[k].z - n4.z) + fabsf(qr_[k].w - n4.w);
        }
        unsafeAtomicAdd(&ia[la], valid ? sA : 0.f);   // both half-lanes contribute
        unsafeAtomicAdd(&ib[lb], valid ? sB : 0.f);

        if (pf) {
            asm volatile("s_waitcnt vmcnt(0)" ::: "memory");
            __builtin_amdgcn_sched_barrier(0);
            write_tile(pt, P, lw);
            write_tile(qt, Q, lw);
        }
    }
    __syncthreads();
    if (t < CDIM) {
        unsafeAtomicAdd(&ws[2112 + t], ia[t]);
        unsafeAtomicAdd(&ws[2144 + t], ib[t]);
    }
}

__global__ __launch_bounds__(64) void finalize_kernel(
    const float* __restrict__ ws, float* __restrict__ out, int nrows)
{
    __shared__ float tota[CDIM];
    __shared__ float totb[CDIM];
    int t = threadIdx.x;   // lanes 0..31 = tensor a, 32..63 = tensor b
    if (t < CDIM) {
        float sa_ = 0.f, sb_ = 0.f;
        for (int c = 0; c < CDIM; c++) {
            sa_ += ws[64 + c * 32 + t];
            sb_ += ws[64 + 1024 + c * 32 + t];
        }
        tota[t] = sa_; totb[t] = sb_;
    }
    __syncthreads();

    const int  c   = t & 31;
    const bool isA = (t < 32);
    const float* sums = isA ? (ws + 64) : (ws + 64 + 1024);
    const float* tot  = isA ? tota : totb;
    float cnt  = isA ? ws[c]        : ws[32 + c];
    float isum = isA ? ws[2112 + c] : ws[2144 + c];

    float safe = fmaxf(cnt, 1.0f);
    float invs = 1.0f / safe;
    float invo = 1.0f / fmaxf((float)nrows - cnt, 1.0f);
    float mad = 0.f;
    for (int d = 0; d < CDIM; d++) {
        float s = sums[c * 32 + d];
        float m = s * invs;
        float o = (tot[d] - s) * invo;
        mad += fabsf(m - o);
    }
    mad *= (1.0f / CDIM);
    float diff = expf(-5.0f * mad);
    float present = (cnt > 0.f) ? 1.f : 0.f;

    unsigned long long pm = __ballot(cnt > 0.f);
    int np = isA ? __popcll(pm & 0xFFFFFFFFull) : __popcll(pm >> 32);
    if (np <= 1) diff = 1.0f;

    float intra   = isum * invs * (1.0f / CDIM);
    float contrib = present * (intra + diff);
    float pres    = present;
#pragma unroll
    for (int m = 1; m < 64; m <<= 1) {
        contrib += __shfl_xor(contrib, m, 64);
        pres    += __shfl_xor(pres,    m, 64);
    }
    if (t == 0) out[0] = contrib / (2.0f * pres);
}

extern "C" void kernel_launch(void* const* d_in, const int* in_sizes, int n_in,
                              void* d_out, int out_size, void* d_ws, size_t ws_size,
                              hipStream_t stream) {
    const float* pred   = (const float*)d_in[0];
    const float* pseudo = (const float*)d_in[1];
    float* ws  = (float*)d_ws;
    float* out = (float*)d_out;
    const int nrows = in_sizes[0] / CDIM;   // 2,000,000

    hipMemsetAsync(d_ws, 0, 2176 * sizeof(float), stream);

    dim3 grid(NBLK), block(256);
    pass1_kernel<<<grid, block, 0, stream>>>(pred, pseudo, ws, nrows);
    pass2_kernel<<<grid, block, 0, stream>>>(pred, pseudo, ws, nrows);
    finalize_kernel<<<1, 64, 0, stream>>>(ws, out, nrows);
}